// Round 3
// baseline (371.652 us; speedup 1.0000x reference)
//
#include <hip/hip_runtime.h>
#include <hip/hip_cooperative_groups.h>
#include <float.h>
#include <math.h>

namespace cg = cooperative_groups;

// Problem constants (S=4096 tokens, E=64 experts, CAP=128)
#define SS 4096
#define EE 64
#define CAPC 128
#define ROW 8192                  // E*CAP floats per token per tensor
#define SEC (4096LL * 64 * 128)   // elements per [S,E,C] tensor
#define NBLK 256
#define TPB 1024
#define TPB_TOK 16                // tokens per block

// ---------------------------------------------------------------------------
// Single fused cooperative kernel.
// Phase 1: gate (1 wave/token) + local ranks/counts in LDS + zero own rows.
// Phase 2: block 0: per-expert exclusive prefix over the 256 block counts
//          (global cumsum == block-offset + local rank) + l_aux.
// Phase 3: each block scatters its own tokens' <=2 entries from LDS state.
// LDS persists across grid.sync(), so per-token state never touches HBM.
// ---------------------------------------------------------------------------
__global__ __launch_bounds__(1024) void fused_kernel(
    const float* __restrict__ logits,
    const float* __restrict__ noise,
    int*   __restrict__ bc1,      // [256][64] per-block expert counts (top1)
    int*   __restrict__ bc2,      // [256][64] (top2)
    int*   __restrict__ boff1,    // [256][64] exclusive prefix of bc1
    int*   __restrict__ boff2,    // [256][64] exclusive prefix of bc2
    int*   __restrict__ count1,   // [64] total top1 count per expert
    float* __restrict__ pg,       // [256][64] per-block gate sums
    float* __restrict__ out)
{
    cg::grid_group grid = cg::this_grid();
    const int tid  = threadIdx.x;
    const int wave = tid >> 6;
    const int lane = tid & 63;
    const int b    = blockIdx.x;

    __shared__ int   s_idx1[TPB_TOK], s_idx2[TPB_TOK];
    __shared__ int   s_lr1[TPB_TOK],  s_lr2[TPB_TOK];
    __shared__ float s_g1[TPB_TOK],   s_g2[TPB_TOK];
    __shared__ float s_gate[TPB_TOK][64];
    __shared__ float s_red[16][64];
    __shared__ float s_laux;

    // ---- Phase 1a: gate for token s = b*16 + wave (lane = expert) ----
    const int s = b * TPB_TOK + wave;
    const float l = logits[s * EE + lane];
    const float n = noise [s * EE + lane];

    // argmax over logits, first-index tie-break
    float v = l; int bi = lane;
    #pragma unroll
    for (int off = 32; off; off >>= 1) {
        float v2 = __shfl_xor(v, off, 64);
        int   i2 = __shfl_xor(bi, off, 64);
        if (v2 > v || (v2 == v && i2 < bi)) { v = v2; bi = i2; }
    }
    const int idx1 = bi;

    float e = expf(l - v);
    float sum = e;
    #pragma unroll
    for (int off = 32; off; off >>= 1) sum += __shfl_xor(sum, off, 64);
    const float gate = e / sum;

    // top-2 from logits+noise with top-1 masked to -FLT_MAX
    float lw = (lane == idx1) ? -FLT_MAX : (l + n);
    float v2v = lw; int bi2 = lane;
    #pragma unroll
    for (int off = 32; off; off >>= 1) {
        float q  = __shfl_xor(v2v, off, 64);
        int   i2 = __shfl_xor(bi2, off, 64);
        if (q > v2v || (q == v2v && i2 < bi2)) { v2v = q; bi2 = i2; }
    }
    const int idx2 = bi2;

    s_gate[wave][lane] = gate;
    const float g1v = __shfl(gate, idx1, 64);
    const float g2v = __shfl(gate, idx2, 64);
    if (lane == 0) {
        s_idx1[wave] = idx1;
        s_idx2[wave] = idx2;
        s_g1[wave] = g1v;
        s_g2[wave] = g2v;
    }
    __syncthreads();

    // ---- Phase 1b: block expert counts + gate sums + local ranks ----
    if (tid < 64) {
        int c1 = 0, c2 = 0;
        float gs = 0.f;
        #pragma unroll
        for (int j = 0; j < TPB_TOK; ++j) {
            c1 += (s_idx1[j] == tid);
            c2 += (s_idx2[j] == tid);
            gs += s_gate[j][tid];
        }
        bc1[b * 64 + tid] = c1;
        bc2[b * 64 + tid] = c2;
        pg [b * 64 + tid] = gs;
    } else if (tid < 64 + TPB_TOK) {
        const int t = tid - 64;
        const int m1 = s_idx1[t], m2 = s_idx2[t];
        int r1 = 0, r2 = 0;
        for (int j = 0; j < t; ++j) {
            r1 += (s_idx1[j] == m1);
            r2 += (s_idx2[j] == m2);
        }
        s_lr1[t] = r1;
        s_lr2[t] = r2;
    }

    // ---- Phase 1c: zero this block's 16 combine rows + 16 mask rows ----
    // Region starts at out + 1 + b*131072 (offset 1 mod 4):
    // 3 head scalars + 32767 float4 + 1 tail scalar per tensor.
    {
        const long cb = (long)b * (TPB_TOK * ROW);
        float4* p4 = (float4*)(out + cb + 4);
        float4* q4 = (float4*)(out + SEC + cb + 4);
        const float4 z = make_float4(0.f, 0.f, 0.f, 0.f);
        for (int i = tid; i < 32767; i += TPB) p4[i] = z;
        for (int i = tid; i < 32767; i += TPB) q4[i] = z;
        if (tid < 3) {
            out[cb + 1 + tid] = 0.f;
            out[SEC + cb + 1 + tid] = 0.f;
        } else if (tid == 3) {
            out[cb + (long)TPB_TOK * ROW] = 0.f;
            out[SEC + cb + (long)TPB_TOK * ROW] = 0.f;
        }
    }

    grid.sync();

    // ---- Phase 2: block 0 only: prefix scans + l_aux ----
    if (b == 0) {
        {   // 2-level reduce of pg: 1024 threads -> s_red[16][64]
            const int e = tid & 63, g = tid >> 6;
            float acc = 0.f;
            #pragma unroll
            for (int k = 0; k < 16; ++k) acc += pg[(g * 16 + k) * 64 + e];
            s_red[g][e] = acc;
        }
        __syncthreads();
        if (tid < 64) {
            int o1 = 0;
            for (int blk = 0; blk < NBLK; ++blk) {
                boff1[blk * 64 + tid] = o1;
                o1 += bc1[blk * 64 + tid];
            }
            count1[tid] = o1;
            float gs = 0.f;
            #pragma unroll
            for (int g = 0; g < 16; ++g) gs += s_red[g][tid];
            float prod = gs * (float)o1;
            #pragma unroll
            for (int off = 32; off; off >>= 1) prod += __shfl_xor(prod, off, 64);
            if (tid == 0)
                s_laux = prod * (float)EE / ((float)SS * (float)SS);
        } else if (tid < 128) {
            const int e2 = tid - 64;
            int o2 = 0;
            for (int blk = 0; blk < NBLK; ++blk) {
                boff2[blk * 64 + e2] = o2;
                o2 += bc2[blk * 64 + e2];
            }
        }
    }

    grid.sync();

    // ---- Phase 3: scatter own tokens from LDS state ----
    if (tid < TPB_TOK) {
        const int t  = tid;
        const int i1 = s_idx1[t], i2 = s_idx2[t];
        const int loc1 = s_lr1[t] + boff1[b * 64 + i1];
        const int loc2 = s_lr2[t] + boff2[b * 64 + i2] + count1[i2];
        float g1 = s_g1[t], g2 = s_g2[t];
        const bool k1 = loc1 < CAPC, k2 = loc2 < CAPC;
        g1 = k1 ? g1 : 0.f;
        g2 = k2 ? g2 : 0.f;
        const float denom = fmaxf(g1 + g2, 1.1920929e-07f);  // finfo(f32).eps
        g1 /= denom;
        g2 /= denom;
        float* combine = out + 1;
        float* mask    = out + 1 + SEC;
        const long base = (long)(b * TPB_TOK + t) * ROW;
        if (k1 && g1 != 0.f) {
            const long p = base + (long)i1 * CAPC + loc1;
            combine[p] = g1;
            mask[p]    = 1.f;
        }
        if (k2 && g2 != 0.f) {
            const long p = base + (long)i2 * CAPC + loc2;
            combine[p] = g2;
            mask[p]    = 1.f;
        }
    } else if (tid == TPB_TOK && b == 0) {
        out[0] = s_laux;
    }
}

// ---------------------------------------------------------------------------
// Launch
// ---------------------------------------------------------------------------
extern "C" void kernel_launch(void* const* d_in, const int* in_sizes, int n_in,
                              void* d_out, int out_size, void* d_ws, size_t ws_size,
                              hipStream_t stream) {
    const float* logits = (const float*)d_in[0];
    const float* noise  = (const float*)d_in[1];
    float* out = (float*)d_out;

    char* ws = (char*)d_ws;
    int*   bc1    = (int*)  (ws + 0);        // 64 KB
    int*   bc2    = (int*)  (ws + 65536);    // 64 KB
    int*   boff1  = (int*)  (ws + 131072);   // 64 KB
    int*   boff2  = (int*)  (ws + 196608);   // 64 KB
    int*   count1 = (int*)  (ws + 262144);   // 256 B
    float* pg     = (float*)(ws + 266240);   // 64 KB

    void* args[] = {(void*)&logits, (void*)&noise, (void*)&bc1, (void*)&bc2,
                    (void*)&boff1, (void*)&boff2, (void*)&count1, (void*)&pg,
                    (void*)&out};
    hipLaunchCooperativeKernel((const void*)fused_kernel, dim3(NBLK), dim3(TPB),
                               args, 0, stream);
}

// Round 4
// 288.818 us; speedup vs baseline: 1.2868x; 1.2868x over previous
//
#include <hip/hip_runtime.h>
#include <float.h>
#include <math.h>

// Problem constants (S=4096 tokens, E=64 experts, CAP=128)
#define SS 4096
#define EE 64
#define CAPC 128
#define ROW 8192                  // E*CAP floats per token per tensor
#define SEC (4096LL * 64 * 128)   // elements per [S,E,C] tensor
#define NBLK 256
#define TPB_TOK 16                // tokens per block in K1/K2

// ---------------------------------------------------------------------------
// K1: gate + local ranks + per-block counts, and zero this block's 32 rows.
// 256 blocks x 1024 threads; wave = token (16 tokens/block), lane = expert.
// Per-token state packed to ws: tokmeta[s] = idx1 | idx2<<6 | lr1<<12 | lr2<<17,
// tokg[s] = (g1_raw, g2_raw).
// ---------------------------------------------------------------------------
__global__ __launch_bounds__(1024) void k1_gate_zero(
    const float* __restrict__ logits,
    const float* __restrict__ noise,
    int*   __restrict__ bc1,      // [256][64] per-block top1 counts
    int*   __restrict__ bc2,      // [256][64] per-block top2 counts
    float* __restrict__ pg,       // [256][64] per-block gate sums
    int*   __restrict__ tokmeta,  // [4096] packed idx/ranks
    float2* __restrict__ tokg,    // [4096] raw g1,g2
    float* __restrict__ out)
{
    const int tid  = threadIdx.x;
    const int wave = tid >> 6;
    const int lane = tid & 63;
    const int b    = blockIdx.x;

    __shared__ int   s_idx1[TPB_TOK], s_idx2[TPB_TOK];
    __shared__ float s_gate[TPB_TOK][64];

    // ---- gate for token s = b*16 + wave ----
    const int s = b * TPB_TOK + wave;
    const float l = logits[s * EE + lane];
    const float n = noise [s * EE + lane];

    // argmax over logits, first-index tie-break (all lanes agree)
    float v = l; int bi = lane;
    #pragma unroll
    for (int off = 32; off; off >>= 1) {
        float v2 = __shfl_xor(v, off, 64);
        int   i2 = __shfl_xor(bi, off, 64);
        if (v2 > v || (v2 == v && i2 < bi)) { v = v2; bi = i2; }
    }
    const int idx1 = bi;

    float e = expf(l - v);
    float sum = e;
    #pragma unroll
    for (int off = 32; off; off >>= 1) sum += __shfl_xor(sum, off, 64);
    const float gate = e / sum;

    // top-2 from logits+noise with top-1 masked to -FLT_MAX
    float lw = (lane == idx1) ? -FLT_MAX : (l + n);
    float v2v = lw; int bi2 = lane;
    #pragma unroll
    for (int off = 32; off; off >>= 1) {
        float q  = __shfl_xor(v2v, off, 64);
        int   i2 = __shfl_xor(bi2, off, 64);
        if (q > v2v || (q == v2v && i2 < bi2)) { v2v = q; bi2 = i2; }
    }
    const int idx2 = bi2;

    s_gate[wave][lane] = gate;
    const float g1v = __shfl(gate, idx1, 64);
    const float g2v = __shfl(gate, idx2, 64);
    if (lane == 0) {
        s_idx1[wave] = idx1;
        s_idx2[wave] = idx2;
        tokg[s] = make_float2(g1v, g2v);
    }
    __syncthreads();

    // ---- per-block expert counts + gate sums, local ranks ----
    if (tid < 64) {
        int c1 = 0, c2 = 0;
        float gs = 0.f;
        #pragma unroll
        for (int j = 0; j < TPB_TOK; ++j) {
            c1 += (s_idx1[j] == tid);
            c2 += (s_idx2[j] == tid);
            gs += s_gate[j][tid];
        }
        bc1[b * 64 + tid] = c1;
        bc2[b * 64 + tid] = c2;
        pg [b * 64 + tid] = gs;
    } else if (tid < 64 + TPB_TOK) {
        const int t = tid - 64;
        const int m1 = s_idx1[t], m2 = s_idx2[t];
        int r1 = 0, r2 = 0;
        for (int j = 0; j < t; ++j) {
            r1 += (s_idx1[j] == m1);
            r2 += (s_idx2[j] == m2);
        }
        tokmeta[b * TPB_TOK + t] = m1 | (m2 << 6) | (r1 << 12) | (r2 << 17);
    }

    // ---- zero this block's 16 combine rows + 16 mask rows ----
    // Region starts at out + 1 + b*131072 (offset 1 mod 4):
    // 3 head scalars + 32767 float4 + 1 tail scalar per tensor.
    {
        const long cb = (long)b * (TPB_TOK * ROW);
        float4* p4 = (float4*)(out + cb + 4);
        float4* q4 = (float4*)(out + SEC + cb + 4);
        const float4 z = make_float4(0.f, 0.f, 0.f, 0.f);
        for (int i = tid; i < 32767; i += 1024) p4[i] = z;
        for (int i = tid; i < 32767; i += 1024) q4[i] = z;
        if (tid < 3) {
            out[cb + 1 + tid] = 0.f;
            out[SEC + cb + 1 + tid] = 0.f;
        } else if (tid == 3) {
            out[cb + (long)TPB_TOK * ROW] = 0.f;
            out[SEC + cb + (long)TPB_TOK * ROW] = 0.f;
        }
    }
}

// ---------------------------------------------------------------------------
// K2: redundant per-block prefix scan (bc arrays are L2-resident) + scatter
// of this block's 16 tokens. Block 0 also computes l_aux.
// 256 blocks x 256 threads.
// ---------------------------------------------------------------------------
__global__ __launch_bounds__(256) void k2_scan_scatter(
    const int*   __restrict__ bc1,
    const int*   __restrict__ bc2,
    const float* __restrict__ pg,
    const int*   __restrict__ tokmeta,
    const float2* __restrict__ tokg,
    float* __restrict__ out)
{
    const int tid = threadIdx.x;
    const int b   = blockIdx.x;

    __shared__ int   s_off1[64], s_off2[64], s_cnt1[64];
    __shared__ float s_gs[64];

    if (tid < 64) {
        // exclusive prefix of bc1 over blocks, capture own offset + total
        int o1 = 0, mine = 0;
        #pragma unroll 8
        for (int blk = 0; blk < NBLK; ++blk) {
            if (blk == b) mine = o1;
            o1 += bc1[blk * 64 + tid];
        }
        s_off1[tid] = mine;
        s_cnt1[tid] = o1;
    } else if (tid < 128) {
        const int e = tid - 64;
        int o2 = 0, mine = 0;
        #pragma unroll 8
        for (int blk = 0; blk < NBLK; ++blk) {
            if (blk == b) mine = o2;
            o2 += bc2[blk * 64 + e];
        }
        s_off2[e] = mine;
    } else if (tid < 192 && b == 0) {
        const int e = tid - 128;
        float gs = 0.f;
        #pragma unroll 8
        for (int blk = 0; blk < NBLK; ++blk) gs += pg[blk * 64 + e];
        s_gs[e] = gs;
    }
    __syncthreads();

    if (tid < TPB_TOK) {
        const int s = b * TPB_TOK + tid;
        const int m = tokmeta[s];
        const int i1  =  m        & 63;
        const int i2  = (m >> 6)  & 63;
        const int lr1 = (m >> 12) & 31;
        const int lr2 = (m >> 17) & 31;
        const float2 g = tokg[s];
        const int loc1 = lr1 + s_off1[i1];
        const int loc2 = lr2 + s_off2[i2] + s_cnt1[i2];
        float g1 = g.x, g2 = g.y;
        const bool k1 = loc1 < CAPC, k2 = loc2 < CAPC;
        g1 = k1 ? g1 : 0.f;
        g2 = k2 ? g2 : 0.f;
        const float denom = fmaxf(g1 + g2, 1.1920929e-07f);  // finfo(f32).eps
        g1 /= denom;
        g2 /= denom;
        float* combine = out + 1;
        float* mask    = out + 1 + SEC;
        const long base = (long)s * ROW;
        if (k1 && g1 != 0.f) {
            const long p = base + (long)i1 * CAPC + loc1;
            combine[p] = g1;
            mask[p]    = 1.f;
        }
        if (k2 && g2 != 0.f) {
            const long p = base + (long)i2 * CAPC + loc2;
            combine[p] = g2;
            mask[p]    = 1.f;
        }
    } else if (tid == 64 + TPB_TOK && b == 0) {
        // l_aux = (E / S^2) * sum_e gs_e * cnt1_e  (wave 1 computed s_gs? no:
        // threads 128..191 computed s_gs only for b==0; we are in wave 1)
        float prod = 0.f;
        #pragma unroll 8
        for (int e = 0; e < 64; ++e) prod += s_gs[e] * (float)s_cnt1[e];
        out[0] = prod * (float)EE / ((float)SS * (float)SS);
    }
}

// ---------------------------------------------------------------------------
// Launch
// ---------------------------------------------------------------------------
extern "C" void kernel_launch(void* const* d_in, const int* in_sizes, int n_in,
                              void* d_out, int out_size, void* d_ws, size_t ws_size,
                              hipStream_t stream) {
    const float* logits = (const float*)d_in[0];
    const float* noise  = (const float*)d_in[1];
    float* out = (float*)d_out;

    char* ws = (char*)d_ws;
    int*    bc1     = (int*)   (ws + 0);        // 64 KB
    int*    bc2     = (int*)   (ws + 65536);    // 64 KB
    float*  pg      = (float*) (ws + 131072);   // 64 KB
    int*    tokmeta = (int*)   (ws + 196608);   // 16 KB
    float2* tokg    = (float2*)(ws + 212992);   // 32 KB

    k1_gate_zero<<<NBLK, 1024, 0, stream>>>(logits, noise, bc1, bc2, pg,
                                            tokmeta, tokg, out);
    k2_scan_scatter<<<NBLK, 256, 0, stream>>>(bc1, bc2, pg, tokmeta, tokg, out);
}

// Round 5
// 280.810 us; speedup vs baseline: 1.3235x; 1.0285x over previous
//
#include <hip/hip_runtime.h>
#include <float.h>
#include <math.h>

// Problem constants (S=4096 tokens, E=64 experts, CAP=128)
#define SS 4096
#define EE 64
#define CAPC 128
#define ROW 8192                  // E*CAP floats per token per tensor
#define SEC (4096LL * 64 * 128)   // elements per [S,E,C] tensor
#define NBLK 256
#define TPB_TOK 16                // tokens per block

// ---------------------------------------------------------------------------
// K1: gate + local ranks + per-block counts. No output-tensor writes.
// 256 blocks x 1024 threads; wave = token (16 tokens/block), lane = expert.
// tokmeta[s] = idx1 | idx2<<6 | lr1<<12 | lr2<<17 ; tokg[s] = (g1_raw, g2_raw)
// ---------------------------------------------------------------------------
__global__ __launch_bounds__(1024) void k1_gate(
    const float* __restrict__ logits,
    const float* __restrict__ noise,
    int*   __restrict__ bc1,      // [256][64] per-block top1 counts
    int*   __restrict__ bc2,      // [256][64] per-block top2 counts
    float* __restrict__ pg,       // [256][64] per-block gate sums
    int*   __restrict__ tokmeta,  // [4096] packed idx/ranks
    float2* __restrict__ tokg)    // [4096] raw g1,g2
{
    const int tid  = threadIdx.x;
    const int wave = tid >> 6;
    const int lane = tid & 63;
    const int b    = blockIdx.x;

    __shared__ int   s_idx1[TPB_TOK], s_idx2[TPB_TOK];
    __shared__ float s_gate[TPB_TOK][64];

    // ---- gate for token s = b*16 + wave ----
    const int s = b * TPB_TOK + wave;
    const float l = logits[s * EE + lane];
    const float n = noise [s * EE + lane];

    // argmax over logits, first-index tie-break (all lanes agree)
    float v = l; int bi = lane;
    #pragma unroll
    for (int off = 32; off; off >>= 1) {
        float v2 = __shfl_xor(v, off, 64);
        int   i2 = __shfl_xor(bi, off, 64);
        if (v2 > v || (v2 == v && i2 < bi)) { v = v2; bi = i2; }
    }
    const int idx1 = bi;

    float e = expf(l - v);
    float sum = e;
    #pragma unroll
    for (int off = 32; off; off >>= 1) sum += __shfl_xor(sum, off, 64);
    const float gate = e / sum;

    // top-2 from logits+noise with top-1 masked to -FLT_MAX
    float lw = (lane == idx1) ? -FLT_MAX : (l + n);
    float v2v = lw; int bi2 = lane;
    #pragma unroll
    for (int off = 32; off; off >>= 1) {
        float q  = __shfl_xor(v2v, off, 64);
        int   i2 = __shfl_xor(bi2, off, 64);
        if (q > v2v || (q == v2v && i2 < bi2)) { v2v = q; bi2 = i2; }
    }
    const int idx2 = bi2;

    s_gate[wave][lane] = gate;
    const float g1v = __shfl(gate, idx1, 64);
    const float g2v = __shfl(gate, idx2, 64);
    if (lane == 0) {
        s_idx1[wave] = idx1;
        s_idx2[wave] = idx2;
        tokg[s] = make_float2(g1v, g2v);
    }
    __syncthreads();

    // ---- per-block expert counts + gate sums, local ranks ----
    if (tid < 64) {
        int c1 = 0, c2 = 0;
        float gs = 0.f;
        #pragma unroll
        for (int j = 0; j < TPB_TOK; ++j) {
            c1 += (s_idx1[j] == tid);
            c2 += (s_idx2[j] == tid);
            gs += s_gate[j][tid];
        }
        bc1[b * 64 + tid] = c1;
        bc2[b * 64 + tid] = c2;
        pg [b * 64 + tid] = gs;
    } else if (tid < 64 + TPB_TOK) {
        const int t = tid - 64;
        const int m1 = s_idx1[t], m2 = s_idx2[t];
        int r1 = 0, r2 = 0;
        for (int j = 0; j < t; ++j) {
            r1 += (s_idx1[j] == m1);
            r2 += (s_idx2[j] == m2);
        }
        tokmeta[b * TPB_TOK + t] = m1 | (m2 << 6) | (r1 << 12) | (r2 << 17);
    }
}

// ---------------------------------------------------------------------------
// K2: redundant per-block prefix scan (bc arrays are L2-resident) + scatter
// of this block's 16 tokens. Block 0 also computes l_aux.
// 256 blocks x 256 threads. Runs after the output memset.
// ---------------------------------------------------------------------------
__global__ __launch_bounds__(256) void k2_scan_scatter(
    const int*   __restrict__ bc1,
    const int*   __restrict__ bc2,
    const float* __restrict__ pg,
    const int*   __restrict__ tokmeta,
    const float2* __restrict__ tokg,
    float* __restrict__ out)
{
    const int tid = threadIdx.x;
    const int b   = blockIdx.x;

    __shared__ int   s_off1[64], s_off2[64], s_cnt1[64];
    __shared__ float s_gs[64];

    if (tid < 64) {
        // exclusive prefix of bc1 over blocks, capture own offset + total
        int o1 = 0, mine = 0;
        #pragma unroll 8
        for (int blk = 0; blk < NBLK; ++blk) {
            if (blk == b) mine = o1;
            o1 += bc1[blk * 64 + tid];
        }
        s_off1[tid] = mine;
        s_cnt1[tid] = o1;
    } else if (tid < 128) {
        const int e = tid - 64;
        int o2 = 0, mine = 0;
        #pragma unroll 8
        for (int blk = 0; blk < NBLK; ++blk) {
            if (blk == b) mine = o2;
            o2 += bc2[blk * 64 + e];
        }
        s_off2[e] = mine;
    } else if (tid < 192 && b == 0) {
        const int e = tid - 128;
        float gs = 0.f;
        #pragma unroll 8
        for (int blk = 0; blk < NBLK; ++blk) gs += pg[blk * 64 + e];
        s_gs[e] = gs;
    }
    __syncthreads();

    if (tid < TPB_TOK) {
        const int s = b * TPB_TOK + tid;
        const int m = tokmeta[s];
        const int i1  =  m        & 63;
        const int i2  = (m >> 6)  & 63;
        const int lr1 = (m >> 12) & 31;
        const int lr2 = (m >> 17) & 31;
        const float2 g = tokg[s];
        const int loc1 = lr1 + s_off1[i1];
        const int loc2 = lr2 + s_off2[i2] + s_cnt1[i2];
        float g1 = g.x, g2 = g.y;
        const bool k1 = loc1 < CAPC, k2 = loc2 < CAPC;
        g1 = k1 ? g1 : 0.f;
        g2 = k2 ? g2 : 0.f;
        const float denom = fmaxf(g1 + g2, 1.1920929e-07f);  // finfo(f32).eps
        g1 /= denom;
        g2 /= denom;
        float* combine = out + 1;
        float* mask    = out + 1 + SEC;
        const long base = (long)s * ROW;
        if (k1 && g1 != 0.f) {
            const long p = base + (long)i1 * CAPC + loc1;
            combine[p] = g1;
            mask[p]    = 1.f;
        }
        if (k2 && g2 != 0.f) {
            const long p = base + (long)i2 * CAPC + loc2;
            combine[p] = g2;
            mask[p]    = 1.f;
        }
    } else if (tid == 64 + TPB_TOK && b == 0) {
        // l_aux = (E / S^2) * sum_e gs_e * cnt1_e
        float prod = 0.f;
        #pragma unroll 8
        for (int e = 0; e < 64; ++e) prod += s_gs[e] * (float)s_cnt1[e];
        out[0] = prod * (float)EE / ((float)SS * (float)SS);
    }
}

// ---------------------------------------------------------------------------
// Launch: gate -> memset(out) -> scan+scatter.
// hipMemsetAsync is graph-capturable (memset node) and runs the runtime's
// tuned fill kernel at ~6.6 TB/s — measured faster than any hand-rolled
// zero embedded in a compute kernel.
// ---------------------------------------------------------------------------
extern "C" void kernel_launch(void* const* d_in, const int* in_sizes, int n_in,
                              void* d_out, int out_size, void* d_ws, size_t ws_size,
                              hipStream_t stream) {
    const float* logits = (const float*)d_in[0];
    const float* noise  = (const float*)d_in[1];
    float* out = (float*)d_out;

    char* ws = (char*)d_ws;
    int*    bc1     = (int*)   (ws + 0);        // 64 KB
    int*    bc2     = (int*)   (ws + 65536);    // 64 KB
    float*  pg      = (float*) (ws + 131072);   // 64 KB
    int*    tokmeta = (int*)   (ws + 196608);   // 16 KB
    float2* tokg    = (float2*)(ws + 212992);   // 32 KB

    k1_gate<<<NBLK, 1024, 0, stream>>>(logits, noise, bc1, bc2, pg,
                                       tokmeta, tokg);
    hipMemsetAsync(d_out, 0, (size_t)out_size * sizeof(float), stream);
    k2_scan_scatter<<<NBLK, 256, 0, stream>>>(bc1, bc2, pg, tokmeta, tokg, out);
}

// Round 6
// 274.395 us; speedup vs baseline: 1.3544x; 1.0234x over previous
//
#include <hip/hip_runtime.h>
#include <float.h>
#include <math.h>

// Problem constants (S=4096 tokens, E=64 experts, CAP=128)
#define SS 4096
#define EE 64
#define CAPC 128
#define ROW 8192                  // E*CAP floats per token per tensor
#define SEC (4096LL * 64 * 128)   // elements per [S,E,C] tensor
#define NGATE 256                 // gate blocks (16 tokens each)
#define NFILL 4096                // fill blocks (16384 floats = 64 KB each)
#define TPB_TOK 16                // tokens per gate block

// ---------------------------------------------------------------------------
// K1: fused gate + fill.
//   blocks [0, 256):    gate for 16 tokens (4 waves x 4 tokens), local ranks,
//                       per-block expert counts / gate sums -> ws only.
//   blocks [256, 4352): pure fill — zero a contiguous 64 KB slice of out.
// Gate work (~5us) hides under the fill (~41us); fill blocks have no LDS
// prologue or syncs, so they run at fillBuffer-kernel efficiency.
// ---------------------------------------------------------------------------
__global__ __launch_bounds__(256) void k1_gate_fill(
    const float* __restrict__ logits,
    const float* __restrict__ noise,
    int*   __restrict__ bc1,      // [256][64] per-block top1 counts
    int*   __restrict__ bc2,      // [256][64] per-block top2 counts
    float* __restrict__ pg,       // [256][64] per-block gate sums
    int*   __restrict__ tokmeta,  // [4096] packed idx/ranks
    float2* __restrict__ tokg,    // [4096] raw g1,g2
    float* __restrict__ out)
{
    const int tid = threadIdx.x;

    if (blockIdx.x >= NGATE) {
        // ---- pure fill block: zero floats [fb*16384, (fb+1)*16384) ----
        const int fb = blockIdx.x - NGATE;
        float4* p = (float4*)out + (long)fb * 4096;
        const float4 z = make_float4(0.f, 0.f, 0.f, 0.f);
        #pragma unroll
        for (int i = 0; i < 16; ++i) p[i * 256 + tid] = z;
        if (fb == NFILL - 1 && tid == 0) out[2 * SEC] = 0.f;  // last element
        return;
    }

    // ---- gate block: 4 waves, each handles 4 tokens ----
    const int b    = blockIdx.x;
    const int wave = tid >> 6;
    const int lane = tid & 63;

    __shared__ int   s_idx1[TPB_TOK], s_idx2[TPB_TOK];
    __shared__ float s_gate[TPB_TOK][64];

    #pragma unroll
    for (int t4 = 0; t4 < 4; ++t4) {
        const int t = wave * 4 + t4;        // token within block
        const int s = b * TPB_TOK + t;
        const float l = logits[s * EE + lane];
        const float n = noise [s * EE + lane];

        // argmax over logits, first-index tie-break (all lanes agree)
        float v = l; int bi = lane;
        #pragma unroll
        for (int off = 32; off; off >>= 1) {
            float v2 = __shfl_xor(v, off, 64);
            int   i2 = __shfl_xor(bi, off, 64);
            if (v2 > v || (v2 == v && i2 < bi)) { v = v2; bi = i2; }
        }
        const int idx1 = bi;

        float e = expf(l - v);
        float sum = e;
        #pragma unroll
        for (int off = 32; off; off >>= 1) sum += __shfl_xor(sum, off, 64);
        const float gate = e / sum;

        // top-2 from logits+noise with top-1 masked to -FLT_MAX
        float lw = (lane == idx1) ? -FLT_MAX : (l + n);
        float v2v = lw; int bi2 = lane;
        #pragma unroll
        for (int off = 32; off; off >>= 1) {
            float q  = __shfl_xor(v2v, off, 64);
            int   i2 = __shfl_xor(bi2, off, 64);
            if (q > v2v || (q == v2v && i2 < bi2)) { v2v = q; bi2 = i2; }
        }
        const int idx2 = bi2;

        s_gate[t][lane] = gate;
        const float g1v = __shfl(gate, idx1, 64);
        const float g2v = __shfl(gate, idx2, 64);
        if (lane == 0) {
            s_idx1[t] = idx1;
            s_idx2[t] = idx2;
            tokg[s] = make_float2(g1v, g2v);
        }
    }
    __syncthreads();

    // ---- per-block expert counts + gate sums, local ranks ----
    if (tid < 64) {
        int c1 = 0, c2 = 0;
        float gs = 0.f;
        #pragma unroll
        for (int j = 0; j < TPB_TOK; ++j) {
            c1 += (s_idx1[j] == tid);
            c2 += (s_idx2[j] == tid);
            gs += s_gate[j][tid];
        }
        bc1[b * 64 + tid] = c1;
        bc2[b * 64 + tid] = c2;
        pg [b * 64 + tid] = gs;
    } else if (tid < 64 + TPB_TOK) {
        const int t = tid - 64;
        const int m1 = s_idx1[t], m2 = s_idx2[t];
        int r1 = 0, r2 = 0;
        for (int j = 0; j < t; ++j) {
            r1 += (s_idx1[j] == m1);
            r2 += (s_idx2[j] == m2);
        }
        tokmeta[b * TPB_TOK + t] = m1 | (m2 << 6) | (r1 << 12) | (r2 << 17);
    }
}

// ---------------------------------------------------------------------------
// K2: redundant per-block prefix scan (bc arrays are L2-resident) + scatter
// of this block's 16 tokens. Block 0 also computes l_aux.
// 256 blocks x 256 threads. Stream order guarantees out is fully zeroed.
// ---------------------------------------------------------------------------
__global__ __launch_bounds__(256) void k2_scan_scatter(
    const int*   __restrict__ bc1,
    const int*   __restrict__ bc2,
    const float* __restrict__ pg,
    const int*   __restrict__ tokmeta,
    const float2* __restrict__ tokg,
    float* __restrict__ out)
{
    const int tid = threadIdx.x;
    const int b   = blockIdx.x;

    __shared__ int   s_off1[64], s_off2[64], s_cnt1[64];
    __shared__ float s_gs[64];

    if (tid < 64) {
        // exclusive prefix of bc1 over blocks, capture own offset + total
        int o1 = 0, mine = 0;
        #pragma unroll 8
        for (int blk = 0; blk < NGATE; ++blk) {
            if (blk == b) mine = o1;
            o1 += bc1[blk * 64 + tid];
        }
        s_off1[tid] = mine;
        s_cnt1[tid] = o1;
    } else if (tid < 128) {
        const int e = tid - 64;
        int o2 = 0, mine = 0;
        #pragma unroll 8
        for (int blk = 0; blk < NGATE; ++blk) {
            if (blk == b) mine = o2;
            o2 += bc2[blk * 64 + e];
        }
        s_off2[e] = mine;
    } else if (tid < 192 && b == 0) {
        const int e = tid - 128;
        float gs = 0.f;
        #pragma unroll 8
        for (int blk = 0; blk < NGATE; ++blk) gs += pg[blk * 64 + e];
        s_gs[e] = gs;
    }
    __syncthreads();

    if (tid < TPB_TOK) {
        const int s = b * TPB_TOK + tid;
        const int m = tokmeta[s];
        const int i1  =  m        & 63;
        const int i2  = (m >> 6)  & 63;
        const int lr1 = (m >> 12) & 31;
        const int lr2 = (m >> 17) & 31;
        const float2 g = tokg[s];
        const int loc1 = lr1 + s_off1[i1];
        const int loc2 = lr2 + s_off2[i2] + s_cnt1[i2];
        float g1 = g.x, g2 = g.y;
        const bool k1 = loc1 < CAPC, k2 = loc2 < CAPC;
        g1 = k1 ? g1 : 0.f;
        g2 = k2 ? g2 : 0.f;
        const float denom = fmaxf(g1 + g2, 1.1920929e-07f);  // finfo(f32).eps
        g1 /= denom;
        g2 /= denom;
        float* combine = out + 1;
        float* mask    = out + 1 + SEC;
        const long base = (long)s * ROW;
        if (k1 && g1 != 0.f) {
            const long p = base + (long)i1 * CAPC + loc1;
            combine[p] = g1;
            mask[p]    = 1.f;
        }
        if (k2 && g2 != 0.f) {
            const long p = base + (long)i2 * CAPC + loc2;
            combine[p] = g2;
            mask[p]    = 1.f;
        }
    } else if (tid == 64 + TPB_TOK && b == 0) {
        // l_aux = (E / S^2) * sum_e gs_e * cnt1_e
        float prod = 0.f;
        #pragma unroll 8
        for (int e = 0; e < 64; ++e) prod += s_gs[e] * (float)s_cnt1[e];
        out[0] = prod * (float)EE / ((float)SS * (float)SS);
    }
}

// ---------------------------------------------------------------------------
// Launch: fused gate+fill -> scan+scatter.
// ---------------------------------------------------------------------------
extern "C" void kernel_launch(void* const* d_in, const int* in_sizes, int n_in,
                              void* d_out, int out_size, void* d_ws, size_t ws_size,
                              hipStream_t stream) {
    const float* logits = (const float*)d_in[0];
    const float* noise  = (const float*)d_in[1];
    float* out = (float*)d_out;

    char* ws = (char*)d_ws;
    int*    bc1     = (int*)   (ws + 0);        // 64 KB
    int*    bc2     = (int*)   (ws + 65536);    // 64 KB
    float*  pg      = (float*) (ws + 131072);   // 64 KB
    int*    tokmeta = (int*)   (ws + 196608);   // 16 KB
    float2* tokg    = (float2*)(ws + 212992);   // 32 KB

    k1_gate_fill<<<NGATE + NFILL, 256, 0, stream>>>(logits, noise, bc1, bc2, pg,
                                                    tokmeta, tokg, out);
    k2_scan_scatter<<<NGATE, 256, 0, stream>>>(bc1, bc2, pg, tokmeta, tokg, out);
}